// Round 1
// baseline (126.528 us; speedup 1.0000x reference)
//
#include <hip/hip_runtime.h>
#include <hip/hip_bf16.h>
#include <stdint.h>

#define B_DIM 16384
#define H_DIM 512
#define KTOT  1024   // I + H
#define NP    2048   // 4 gates * H

typedef __attribute__((ext_vector_type(8))) short short8;
typedef __attribute__((ext_vector_type(4))) float floatx4;

static __device__ __forceinline__ unsigned short f2bf(float f) {
  // round-to-nearest-even f32 -> bf16
  unsigned int u = __float_as_uint(f);
  u += 0x7fffu + ((u >> 16) & 1u);
  return (unsigned short)(u >> 16);
}

static __device__ __forceinline__ short8 cvt8(floatx4 v0, floatx4 v1) {
  short8 o;
#pragma unroll
  for (int i = 0; i < 4; ++i) {
    o[i]     = (short)f2bf(v0[i]);
    o[i + 4] = (short)f2bf(v1[i]);
  }
  return o;
}

// ---- kernel 1: A = [x | z] as bf16, row-major [B][1024]
__global__ __launch_bounds__(256) void pack_a_kernel(
    const float* __restrict__ x, const float* __restrict__ z,
    unsigned short* __restrict__ Abf) {
  int t   = blockIdx.x * 256 + threadIdx.x;   // one thread = 8 elements
  int b   = t >> 7;                            // 128 groups of 8 per row
  int col = (t & 127) << 3;
  const float* src = (col < 512) ? (x + (uint64_t)b * 512 + col)
                                 : (z + (uint64_t)b * 512 + (col - 512));
  floatx4 v0 = *reinterpret_cast<const floatx4*>(src);
  floatx4 v1 = *reinterpret_cast<const floatx4*>(src + 4);
  *reinterpret_cast<short8*>(Abf + (uint64_t)b * KTOT + col) = cvt8(v0, v1);
}

// ---- kernel 2: packed weights, bf16 [2048][1024].
// Row np -> (gate g, column h) with gate-interleaved fragment order:
//   np = hblock*128 + wc*64 + g*16 + t,  h = hblock*32 + wc*16 + t
// Row contents: k<512 -> W_g[h][k], else U_g[h][k-512].
__global__ __launch_bounds__(256) void pack_w_kernel(
    const float* __restrict__ Wi, const float* __restrict__ Wf,
    const float* __restrict__ Wc, const float* __restrict__ Wo,
    const float* __restrict__ Ui, const float* __restrict__ Uf,
    const float* __restrict__ Uc, const float* __restrict__ Uo,
    unsigned short* __restrict__ Bp) {
  int t  = blockIdx.x * 256 + threadIdx.x;    // one thread = 8 elements
  int np = t >> 7;
  int k  = (t & 127) << 3;
  int hblock = np >> 7;
  int rem    = np & 127;
  int wcc    = rem >> 6;
  int g      = (rem >> 4) & 3;
  int tt     = rem & 15;
  int h      = hblock * 32 + wcc * 16 + tt;
  const float* src;
  if (k < 512) {
    const float* W = (g == 0) ? Wi : (g == 1) ? Wf : (g == 2) ? Wc : Wo;
    src = W + (uint64_t)h * 512 + k;
  } else {
    const float* U = (g == 0) ? Ui : (g == 1) ? Uf : (g == 2) ? Uc : Uo;
    src = U + (uint64_t)h * 512 + (k - 512);
  }
  floatx4 v0 = *reinterpret_cast<const floatx4*>(src);
  floatx4 v1 = *reinterpret_cast<const floatx4*>(src + 4);
  *reinterpret_cast<short8*>(Bp + (uint64_t)np * KTOT + k) = cvt8(v0, v1);
}

// ---- kernel 3: GEMM (M=16384, N=2048, K=1024) + fused LSTM epilogue.
// 128x128 tile, BK=32, 4 waves (2x2), 16x16x32 bf16 MFMA, acc 4x4 frags/wave.
// N-fragment index == gate index, so each lane holds all 4 gates for its
// (row, h) pair -> lane-local epilogue.
__global__ __launch_bounds__(256) void lstm_gemm_kernel(
    const unsigned short* __restrict__ Abf,
    const unsigned short* __restrict__ Bp,
    const float* __restrict__ z,
    const float* __restrict__ b_i, const float* __restrict__ b_f,
    const float* __restrict__ b_c, const float* __restrict__ b_o,
    float* __restrict__ out) {
  __shared__ unsigned short As[128 * 32];
  __shared__ unsigned short Bs[128 * 32];

  int tid = threadIdx.x;
  int bid = blockIdx.x;
  // XCD-aware swizzle: 2048 blocks, 8 XCDs, contiguous 256-block chunk per XCD
  int sw = (bid & 7) * 256 + (bid >> 3);
  int bn = sw & 15;    // 16 N-tiles (each = 32 h columns * 4 gates)
  int bm = sw >> 4;    // 128 M-tiles
  int brow = bm << 7;

  int lane = tid & 63;
  int wid  = tid >> 6;
  int wr   = wid >> 1;   // wave row (0..1) -> 64 rows each
  int wc   = wid & 1;    // wave col (0..1) -> 16 h columns each

  floatx4 acc[4][4];
#pragma unroll
  for (int m = 0; m < 4; ++m)
#pragma unroll
    for (int g = 0; g < 4; ++g)
      acc[m][g] = (floatx4){0.f, 0.f, 0.f, 0.f};

  // staging: element e covers LDS row e>>2, k ((e&3)<<3); 16B per thread, 2 rounds
  int e0 = tid;
  int e1 = 256 + tid;
  const unsigned short* gA0 = Abf + (uint64_t)(brow + (e0 >> 2)) * KTOT + ((e0 & 3) << 3);
  const unsigned short* gA1 = Abf + (uint64_t)(brow + (e1 >> 2)) * KTOT + ((e1 & 3) << 3);
  const unsigned short* gB0 = Bp + (uint64_t)(bn * 128 + (e0 >> 2)) * KTOT + ((e0 & 3) << 3);
  const unsigned short* gB1 = Bp + (uint64_t)(bn * 128 + (e1 >> 2)) * KTOT + ((e1 & 3) << 3);

  int kfr = (lane >> 4) << 3;  // 0,8,16,24
  const unsigned short* pa = As + (wr * 64 + (lane & 15)) * 32 + kfr;
  const unsigned short* pb = Bs + (wc * 64 + (lane & 15)) * 32 + kfr;

  for (int k0 = 0; k0 < KTOT; k0 += 32) {
    __builtin_amdgcn_global_load_lds(
        (const __attribute__((address_space(1))) void*)(gA0 + k0),
        (__attribute__((address_space(3))) void*)(As + e0 * 8), 16, 0, 0);
    __builtin_amdgcn_global_load_lds(
        (const __attribute__((address_space(1))) void*)(gA1 + k0),
        (__attribute__((address_space(3))) void*)(As + e1 * 8), 16, 0, 0);
    __builtin_amdgcn_global_load_lds(
        (const __attribute__((address_space(1))) void*)(gB0 + k0),
        (__attribute__((address_space(3))) void*)(Bs + e0 * 8), 16, 0, 0);
    __builtin_amdgcn_global_load_lds(
        (const __attribute__((address_space(1))) void*)(gB1 + k0),
        (__attribute__((address_space(3))) void*)(Bs + e1 * 8), 16, 0, 0);
    __syncthreads();

    short8 af[4], bfr[4];
#pragma unroll
    for (int m = 0; m < 4; ++m)
      af[m] = *reinterpret_cast<const short8*>(pa + m * 16 * 32);
#pragma unroll
    for (int g = 0; g < 4; ++g)
      bfr[g] = *reinterpret_cast<const short8*>(pb + g * 16 * 32);
#pragma unroll
    for (int m = 0; m < 4; ++m)
#pragma unroll
      for (int g = 0; g < 4; ++g)
        acc[m][g] = __builtin_amdgcn_mfma_f32_16x16x32_bf16(af[m], bfr[g], acc[m][g], 0, 0, 0);
    __syncthreads();
  }

  // ---- fused LSTM epilogue (lane-local: fragment n == gate)
  int h = (bn << 5) + (wc << 4) + (lane & 15);
  float vbi = b_i[h], vbf = b_f[h], vbc = b_c[h], vbo = b_o[h];
  int rbase = brow + (wr << 6) + ((lane >> 4) << 2);
  float* outH = out;
  float* outC = out + (uint64_t)B_DIM * H_DIM;
#pragma unroll
  for (int m = 0; m < 4; ++m) {
#pragma unroll
    for (int j = 0; j < 4; ++j) {
      int r = rbase + (m << 4) + j;
      float pi = acc[m][0][j] + vbi;
      float pf = acc[m][1][j] + vbf;
      float pc = acc[m][2][j] + vbc;
      float po = acc[m][3][j] + vbo;
      float gi = 1.f / (1.f + __expf(-pi));
      float gf = 1.f / (1.f + __expf(-pf));
      float gc = 1.f - 2.f / (__expf(2.f * pc) + 1.f);  // tanh
      float go = 1.f / (1.f + __expf(-po));
      float zv = z[(uint64_t)r * H_DIM + h];
      float cn = gf * zv + gi * gc;
      float hn = go * (1.f - 2.f / (__expf(2.f * cn) + 1.f));
      outH[(uint64_t)r * H_DIM + h] = hn;
      outC[(uint64_t)r * H_DIM + h] = cn;
    }
  }
}

extern "C" void kernel_launch(void* const* d_in, const int* in_sizes, int n_in,
                              void* d_out, int out_size, void* d_ws, size_t ws_size,
                              hipStream_t stream) {
  const float* z  = (const float*)d_in[0];
  const float* x  = (const float*)d_in[1];
  const float* Wi = (const float*)d_in[2];
  const float* Wf = (const float*)d_in[3];
  const float* Wc = (const float*)d_in[4];
  const float* Wo = (const float*)d_in[5];
  const float* bi = (const float*)d_in[6];
  const float* bf = (const float*)d_in[7];
  const float* bc = (const float*)d_in[8];
  const float* bo = (const float*)d_in[9];
  const float* Ui = (const float*)d_in[10];
  const float* Uf = (const float*)d_in[11];
  const float* Uc = (const float*)d_in[12];
  const float* Uo = (const float*)d_in[13];

  unsigned short* Abf = (unsigned short*)d_ws;                         // 32 MB
  unsigned short* Bp  = (unsigned short*)((char*)d_ws
                         + (size_t)B_DIM * KTOT * sizeof(unsigned short)); // +4 MB
  float* out = (float*)d_out;

  hipLaunchKernelGGL(pack_a_kernel, dim3(B_DIM * KTOT / 8 / 256), dim3(256), 0, stream,
                     x, z, Abf);
  hipLaunchKernelGGL(pack_w_kernel, dim3((size_t)NP * KTOT / 8 / 256), dim3(256), 0, stream,
                     Wi, Wf, Wc, Wo, Ui, Uf, Uc, Uo, Bp);
  hipLaunchKernelGGL(lstm_gemm_kernel, dim3(128 * 16), dim3(256), 0, stream,
                     Abf, Bp, z, bi, bf, bc, bo, out);
}

// Round 2
// 125.581 us; speedup vs baseline: 1.0075x; 1.0075x over previous
//
#include <hip/hip_runtime.h>
#include <hip/hip_bf16.h>
#include <stdint.h>

#define B_DIM 16384
#define H_DIM 512
#define KTOT  1024   // I + H
#define NP    2048   // 4 gates * H

typedef __attribute__((ext_vector_type(8))) short short8;
typedef __attribute__((ext_vector_type(4))) float floatx4;

static __device__ __forceinline__ unsigned short f2bf(float f) {
  unsigned int u = __float_as_uint(f);
  u += 0x7fffu + ((u >> 16) & 1u);
  return (unsigned short)(u >> 16);
}

static __device__ __forceinline__ short8 cvt8(floatx4 v0, floatx4 v1) {
  short8 o;
#pragma unroll
  for (int i = 0; i < 4; ++i) {
    o[i]     = (short)f2bf(v0[i]);
    o[i + 4] = (short)f2bf(v1[i]);
  }
  return o;
}

// ---- kernel 1: A = [x | z] packed in MFMA-fragment-linear order.
// Per (bm: 128-row block, kb: 32-k block): 4096 bf16 = 512 units of 8.
// unit = (bm*32+kb)*512 + wr*256 + m*64 + lane; lane=(q,t)
//   -> A row = bm*128 + wr*64 + m*16 + t, k = kb*32 + q*8 + j
__global__ __launch_bounds__(256) void pack_a_kernel(
    const float* __restrict__ x, const float* __restrict__ z,
    unsigned short* __restrict__ Ap) {
  int unit = blockIdx.x * 256 + threadIdx.x;
  int lane = unit & 63;
  int m    = (unit >> 6) & 3;
  int wr   = (unit >> 8) & 1;
  int kb   = (unit >> 9) & 31;
  int bm   = unit >> 14;
  int row  = bm * 128 + wr * 64 + m * 16 + (lane & 15);
  int k    = kb * 32 + ((lane >> 4) << 3);
  const float* src = (k < 512) ? (x + (uint64_t)row * 512 + k)
                               : (z + (uint64_t)row * 512 + (k - 512));
  floatx4 v0 = *reinterpret_cast<const floatx4*>(src);
  floatx4 v1 = *reinterpret_cast<const floatx4*>(src + 4);
  *reinterpret_cast<short8*>(Ap + (uint64_t)unit * 8) = cvt8(v0, v1);
}

// ---- kernel 2: packed weights in fragment-linear order.
// unit = (bn*32+kb)*512 + wc*256 + g*64 + lane; lane=(q,t)
//   -> h = bn*32 + wc*16 + t (gate g), k = kb*32 + q*8 + j
__global__ __launch_bounds__(256) void pack_w_kernel(
    const float* __restrict__ Wi, const float* __restrict__ Wf,
    const float* __restrict__ Wc, const float* __restrict__ Wo,
    const float* __restrict__ Ui, const float* __restrict__ Uf,
    const float* __restrict__ Uc, const float* __restrict__ Uo,
    unsigned short* __restrict__ Bp) {
  int unit = blockIdx.x * 256 + threadIdx.x;
  int lane = unit & 63;
  int g    = (unit >> 6) & 3;
  int wcc  = (unit >> 8) & 1;
  int kb   = (unit >> 9) & 31;
  int bn   = unit >> 14;
  int h    = bn * 32 + wcc * 16 + (lane & 15);
  int k    = kb * 32 + ((lane >> 4) << 3);
  const float* src;
  if (k < 512) {
    const float* W = (g == 0) ? Wi : (g == 1) ? Wf : (g == 2) ? Wc : Wo;
    src = W + (uint64_t)h * 512 + k;
  } else {
    const float* U = (g == 0) ? Ui : (g == 1) ? Uf : (g == 2) ? Uc : Uo;
    src = U + (uint64_t)h * 512 + (k - 512);
  }
  floatx4 v0 = *reinterpret_cast<const floatx4*>(src);
  floatx4 v1 = *reinterpret_cast<const floatx4*>(src + 4);
  *reinterpret_cast<short8*>(Bp + (uint64_t)unit * 8) = cvt8(v0, v1);
}

// ---- kernel 3: GEMM (M=16384, Npacked=2048, K=1024) + fused LSTM epilogue.
// 128x128 tile, BK=64 (2 k-sub-blocks per barrier), 4 waves (2x2),
// 16x16x32 bf16 MFMA. Fragment-linear LDS: all ds_read_b128 are
// base + lane*16B -> conflict-free; global_load_lds staging fully linear.
__global__ __launch_bounds__(256) void lstm_gemm_kernel(
    const unsigned short* __restrict__ Ap,
    const unsigned short* __restrict__ Bp,
    const float* __restrict__ z,
    const float* __restrict__ b_i, const float* __restrict__ b_f,
    const float* __restrict__ b_c, const float* __restrict__ b_o,
    float* __restrict__ out) {
  __shared__ unsigned short As[8192];  // 16 KB = 2 k-sub-blocks of 4096
  __shared__ unsigned short Bs[8192];

  int tid = threadIdx.x;
  int bid = blockIdx.x;
  // XCD-aware swizzle: 2048 blocks, 8 XCDs, contiguous 256-block chunk per XCD
  int sw = (bid & 7) * 256 + (bid >> 3);
  int bn = sw & 15;    // 16 N-tiles (32 h cols * 4 gates each)
  int bm = sw >> 4;    // 128 M-tiles
  int brow = bm << 7;

  int lane = tid & 63;
  int wid  = tid >> 6;
  int wr   = wid >> 1;
  int wc   = wid & 1;

  floatx4 acc[4][4];
#pragma unroll
  for (int m = 0; m < 4; ++m)
#pragma unroll
    for (int g = 0; g < 4; ++g)
      acc[m][g] = (floatx4){0.f, 0.f, 0.f, 0.f};

  const unsigned short* gA = Ap + (uint64_t)bm * (32 * 4096);
  const unsigned short* gB = Bp + (uint64_t)bn * (32 * 4096);

  const unsigned short* pa0 = As + wr * 2048 + lane * 8;
  const unsigned short* pb0 = Bs + wc * 2048 + lane * 8;

  for (int kb = 0; kb < 32; kb += 2) {
    const unsigned short* sA = gA + kb * 4096;
    const unsigned short* sB = gB + kb * 4096;
#pragma unroll
    for (int r = 0; r < 4; ++r) {
      __builtin_amdgcn_global_load_lds(
          (const __attribute__((address_space(1))) void*)(sA + r * 2048 + tid * 8),
          (__attribute__((address_space(3))) void*)(As + r * 2048 + tid * 8), 16, 0, 0);
      __builtin_amdgcn_global_load_lds(
          (const __attribute__((address_space(1))) void*)(sB + r * 2048 + tid * 8),
          (__attribute__((address_space(3))) void*)(Bs + r * 2048 + tid * 8), 16, 0, 0);
    }
    __syncthreads();

#pragma unroll
    for (int kk = 0; kk < 2; ++kk) {
      const unsigned short* pa = pa0 + kk * 4096;
      const unsigned short* pb = pb0 + kk * 4096;
      short8 af[4], bfr[4];
#pragma unroll
      for (int m = 0; m < 4; ++m)
        af[m] = *reinterpret_cast<const short8*>(pa + m * 512);
#pragma unroll
      for (int g = 0; g < 4; ++g)
        bfr[g] = *reinterpret_cast<const short8*>(pb + g * 512);
#pragma unroll
      for (int m = 0; m < 4; ++m)
#pragma unroll
        for (int g = 0; g < 4; ++g)
          acc[m][g] = __builtin_amdgcn_mfma_f32_16x16x32_bf16(af[m], bfr[g], acc[m][g], 0, 0, 0);
    }
    __syncthreads();
  }

  // ---- fused LSTM epilogue (lane-local: fragment index g == gate)
  int h = (bn << 5) + (wc << 4) + (lane & 15);
  float vbi = b_i[h], vbf = b_f[h], vbc = b_c[h], vbo = b_o[h];
  int rbase = brow + (wr << 6) + ((lane >> 4) << 2);
  float* outH = out;
  float* outC = out + (uint64_t)B_DIM * H_DIM;
#pragma unroll
  for (int m = 0; m < 4; ++m) {
#pragma unroll
    for (int j = 0; j < 4; ++j) {
      int r = rbase + (m << 4) + j;
      float pi = acc[m][0][j] + vbi;
      float pf = acc[m][1][j] + vbf;
      float pc = acc[m][2][j] + vbc;
      float po = acc[m][3][j] + vbo;
      float gi = 1.f / (1.f + __expf(-pi));
      float gf = 1.f / (1.f + __expf(-pf));
      float gc = 1.f - 2.f / (__expf(2.f * pc) + 1.f);  // tanh
      float go = 1.f / (1.f + __expf(-po));
      float zv = z[(uint64_t)r * H_DIM + h];
      float cn = gf * zv + gi * gc;
      float hn = go * (1.f - 2.f / (__expf(2.f * cn) + 1.f));
      outH[(uint64_t)r * H_DIM + h] = hn;
      outC[(uint64_t)r * H_DIM + h] = cn;
    }
  }
}

extern "C" void kernel_launch(void* const* d_in, const int* in_sizes, int n_in,
                              void* d_out, int out_size, void* d_ws, size_t ws_size,
                              hipStream_t stream) {
  const float* z  = (const float*)d_in[0];
  const float* x  = (const float*)d_in[1];
  const float* Wi = (const float*)d_in[2];
  const float* Wf = (const float*)d_in[3];
  const float* Wc = (const float*)d_in[4];
  const float* Wo = (const float*)d_in[5];
  const float* bi = (const float*)d_in[6];
  const float* bf = (const float*)d_in[7];
  const float* bc = (const float*)d_in[8];
  const float* bo = (const float*)d_in[9];
  const float* Ui = (const float*)d_in[10];
  const float* Uf = (const float*)d_in[11];
  const float* Uc = (const float*)d_in[12];
  const float* Uo = (const float*)d_in[13];

  unsigned short* Ap = (unsigned short*)d_ws;                          // 32 MB
  unsigned short* Bp = (unsigned short*)((char*)d_ws
                        + (size_t)B_DIM * KTOT * sizeof(unsigned short)); // +4 MB
  float* out = (float*)d_out;

  hipLaunchKernelGGL(pack_w_kernel, dim3((size_t)NP * KTOT / 8 / 256), dim3(256), 0, stream,
                     Wi, Wf, Wc, Wo, Ui, Uf, Uc, Uo, Bp);
  hipLaunchKernelGGL(pack_a_kernel, dim3((size_t)B_DIM * KTOT / 8 / 256), dim3(256), 0, stream,
                     x, z, Ap);
  hipLaunchKernelGGL(lstm_gemm_kernel, dim3(128 * 16), dim3(256), 0, stream,
                     Ap, Bp, z, bi, bf, bc, bo, out);
}

// Round 3
// 104.058 us; speedup vs baseline: 1.2159x; 1.2068x over previous
//
#include <hip/hip_runtime.h>
#include <hip/hip_bf16.h>
#include <stdint.h>

#define B_DIM 16384
#define H_DIM 512
#define KTOT  1024   // I + H
#define NP    2048   // 4 gates * H

typedef __attribute__((ext_vector_type(8))) short short8;
typedef __attribute__((ext_vector_type(4))) float floatx4;

static __device__ __forceinline__ unsigned short f2bf(float f) {
  unsigned int u = __float_as_uint(f);
  u += 0x7fffu + ((u >> 16) & 1u);
  return (unsigned short)(u >> 16);
}

static __device__ __forceinline__ short8 cvt8(floatx4 v0, floatx4 v1) {
  short8 o;
#pragma unroll
  for (int i = 0; i < 4; ++i) {
    o[i]     = (short)f2bf(v0[i]);
    o[i + 4] = (short)f2bf(v1[i]);
  }
  return o;
}

// ---------------------------------------------------------------------------
// Packed A layout (bf16): [bm(64)][kt(16)][mh(2)][wr(2)][m4(4)][kk(2)][lane(64)][8]
//   row = bm*256 + wr*128 + mh*64 + m4*16 + (lane&15)
//   k   = kt*64 + kk*32 + (lane>>4)*8      (k<512 -> x, else z)
// Tile (bm,kt) = 16384 ushorts = 32KB, exactly the LDS A-tile image.
// ---------------------------------------------------------------------------
__global__ __launch_bounds__(256) void pack_a_kernel(
    const float* __restrict__ x, const float* __restrict__ z,
    unsigned short* __restrict__ Ap) {
  int u    = blockIdx.x * 256 + threadIdx.x;
  int lane = u & 63;
  int kk   = (u >> 6) & 1;
  int m4   = (u >> 7) & 3;
  int wr   = (u >> 9) & 1;
  int mh   = (u >> 10) & 1;
  int kt   = (u >> 11) & 15;
  int bm   = u >> 15;
  int row  = bm * 256 + wr * 128 + mh * 64 + m4 * 16 + (lane & 15);
  int k    = kt * 64 + kk * 32 + ((lane >> 4) << 3);
  const float* src = (k < 512) ? (x + (uint64_t)row * 512 + k)
                               : (z + (uint64_t)row * 512 + (k - 512));
  floatx4 v0 = *reinterpret_cast<const floatx4*>(src);
  floatx4 v1 = *reinterpret_cast<const floatx4*>(src + 4);
  *reinterpret_cast<short8*>(Ap + (uint64_t)u * 8) = cvt8(v0, v1);
}

// ---------------------------------------------------------------------------
// Packed B layout (bf16): [bn(8)][kt(16)][nh(2)][wc(4)][n2(2)][kk(2)][lane(64)][8]
//   h = bn*64 + wc*16 + (lane&15); gate g = nh*2 + n2
//   k = kt*64 + kk*32 + (lane>>4)*8    (k<512 -> W_g, else U_g)
// ---------------------------------------------------------------------------
__global__ __launch_bounds__(256) void pack_w_kernel(
    const float* __restrict__ Wi, const float* __restrict__ Wf,
    const float* __restrict__ Wc, const float* __restrict__ Wo,
    const float* __restrict__ Ui, const float* __restrict__ Uf,
    const float* __restrict__ Uc, const float* __restrict__ Uo,
    unsigned short* __restrict__ Bp) {
  int u    = blockIdx.x * 256 + threadIdx.x;
  int lane = u & 63;
  int kk   = (u >> 6) & 1;
  int n2   = (u >> 7) & 1;
  int wc   = (u >> 8) & 3;
  int nh   = (u >> 10) & 1;
  int kt   = (u >> 11) & 15;
  int bn   = u >> 15;
  int h    = bn * 64 + wc * 16 + (lane & 15);
  int g    = nh * 2 + n2;
  int k    = kt * 64 + kk * 32 + ((lane >> 4) << 3);
  const float* src;
  if (k < 512) {
    const float* W = (g == 0) ? Wi : (g == 1) ? Wf : (g == 2) ? Wc : Wo;
    src = W + (uint64_t)h * 512 + k;
  } else {
    const float* U = (g == 0) ? Ui : (g == 1) ? Uf : (g == 2) ? Uc : Uo;
    src = U + (uint64_t)h * 512 + (k - 512);
  }
  floatx4 v0 = *reinterpret_cast<const floatx4*>(src);
  floatx4 v1 = *reinterpret_cast<const floatx4*>(src + 4);
  *reinterpret_cast<short8*>(Bp + (uint64_t)u * 8) = cvt8(v0, v1);
}

// stage one 16KB half-tile: 512 threads x 16B x 2 instructions
static __device__ __forceinline__ void stage2(const unsigned short* g,
                                              unsigned short* l, int tid) {
  __builtin_amdgcn_global_load_lds(
      (const __attribute__((address_space(1))) void*)(g + tid * 8),
      (__attribute__((address_space(3))) void*)(l + tid * 8), 16, 0, 0);
  __builtin_amdgcn_global_load_lds(
      (const __attribute__((address_space(1))) void*)(g + 4096 + tid * 8),
      (__attribute__((address_space(3))) void*)(l + 4096 + tid * 8), 16, 0, 0);
}

#define WAITBAR(S)                                  \
  asm volatile(S ::: "memory");                     \
  __builtin_amdgcn_sched_barrier(0);                \
  __builtin_amdgcn_s_barrier();                     \
  __builtin_amdgcn_sched_barrier(0);

// ---------------------------------------------------------------------------
// GEMM M=16384 Np=2048 K=1024, 256x256 tile, BK=64, 8 waves (2Mx4N),
// 4 phases/K-tile (quadrants), counted vmcnt, double-buffered 128KB LDS.
// Half-tile queue per K-tile, issue order H0=A-lo,H1=B-lo,H2=A-hi,H3=B-hi.
// Steady state (2 loads/half): enter p0 with 4 outstanding (H2,H3 of kt);
//   p0:+H0(kt+1)=6, vmcnt(4) releases H2(kt)  [needed p1]
//   p1:+H1(kt+1)=6, vmcnt(4) releases H3(kt)  [needed p2]
//   p2:+H2(kt+1)=6, no wait                   [p3 reuses A-lo]
//   p3:+H3(kt+1)=8, vmcnt(4) releases H0,H1(kt+1) [needed next p0]
// Last tile: p0 vmcnt(2), p1 vmcnt(0).
// ---------------------------------------------------------------------------
__global__ __launch_bounds__(512, 2) void lstm_gemm_kernel(
    const unsigned short* __restrict__ Ap,
    const unsigned short* __restrict__ Bp,
    const float* __restrict__ z,
    const float* __restrict__ b_i, const float* __restrict__ b_f,
    const float* __restrict__ b_c, const float* __restrict__ b_o,
    float* __restrict__ out) {
  __shared__ unsigned short lds[65536];  // 128KB: [buf(2)][A 16384 | B 16384]

  int tid  = threadIdx.x;
  int bid  = blockIdx.x;
  int sw   = (bid & 7) * 64 + (bid >> 3);  // 512 % 8 == 0 -> bijective
  int bn   = sw & 7;
  int bm   = sw >> 3;
  int lane = tid & 63;
  int wid  = tid >> 6;
  int wr   = wid >> 2;   // 0..1 -> 128 rows
  int wc   = wid & 3;    // 0..3 -> 16 h * 4 gates

  floatx4 acc[8][4];
#pragma unroll
  for (int m = 0; m < 8; ++m)
#pragma unroll
    for (int g = 0; g < 4; ++g)
      acc[m][g] = (floatx4){0.f, 0.f, 0.f, 0.f};

  const unsigned short* gA = Ap + (uint64_t)bm * (16 * 16384);
  const unsigned short* gB = Bp + (uint64_t)bn * (16 * 16384);
  const unsigned short* aRd = lds + wr * 4096 + lane * 8;
  const unsigned short* bRd = lds + 16384 + wc * 2048 + lane * 8;

  // prologue: tile 0 -> buf0, issue order H0,H1,H2,H3
  stage2(gA, lds, tid);                    // H0 A-lo
  stage2(gB, lds + 16384, tid);            // H1 B-lo
  stage2(gA + 8192, lds + 8192, tid);      // H2 A-hi
  stage2(gB + 8192, lds + 24576, tid);     // H3 B-hi
  asm volatile("s_waitcnt vmcnt(4)" ::: "memory");
  __builtin_amdgcn_sched_barrier(0);
  __builtin_amdgcn_s_barrier();
  __builtin_amdgcn_sched_barrier(0);

  int curOff = 0;
  short8 aF[4][2], bF[2][2];

  for (int kt = 0; kt < 16; ++kt) {
    const int nxtOff = curOff ^ 32768;
    const unsigned short* aC = aRd + curOff;
    const unsigned short* bC = bRd + curOff;
    unsigned short* aN = lds + nxtOff;
    unsigned short* bN = lds + nxtOff + 16384;
    const unsigned short* gAn = gA + (kt + 1) * 16384;
    const unsigned short* gBn = gB + (kt + 1) * 16384;
    const bool last = (kt == 15);

    // ---- phase 0: quadrant (mh0, nh0): load A-lo frags + B-lo frags
#pragma unroll
    for (int m4 = 0; m4 < 4; ++m4) {
      aF[m4][0] = *reinterpret_cast<const short8*>(aC + m4 * 1024);
      aF[m4][1] = *reinterpret_cast<const short8*>(aC + m4 * 1024 + 512);
    }
#pragma unroll
    for (int n2 = 0; n2 < 2; ++n2) {
      bF[n2][0] = *reinterpret_cast<const short8*>(bC + n2 * 1024);
      bF[n2][1] = *reinterpret_cast<const short8*>(bC + n2 * 1024 + 512);
    }
    if (!last) stage2(gAn, aN, tid);  // H0(kt+1)
    __builtin_amdgcn_s_setprio(1);
#pragma unroll
    for (int m4 = 0; m4 < 4; ++m4)
#pragma unroll
      for (int n2 = 0; n2 < 2; ++n2)
#pragma unroll
        for (int kk = 0; kk < 2; ++kk)
          acc[m4][n2] = __builtin_amdgcn_mfma_f32_16x16x32_bf16(
              aF[m4][kk], bF[n2][kk], acc[m4][n2], 0, 0, 0);
    __builtin_amdgcn_s_setprio(0);
    if (!last) { WAITBAR("s_waitcnt vmcnt(4) lgkmcnt(0)") }
    else       { WAITBAR("s_waitcnt vmcnt(2) lgkmcnt(0)") }

    // ---- phase 1: quadrant (mh1, nh0): reload A (A-hi), reuse B
#pragma unroll
    for (int m4 = 0; m4 < 4; ++m4) {
      aF[m4][0] = *reinterpret_cast<const short8*>(aC + 8192 + m4 * 1024);
      aF[m4][1] = *reinterpret_cast<const short8*>(aC + 8192 + m4 * 1024 + 512);
    }
    if (!last) stage2(gBn, bN, tid);  // H1(kt+1)
    __builtin_amdgcn_s_setprio(1);
#pragma unroll
    for (int m4 = 0; m4 < 4; ++m4)
#pragma unroll
      for (int n2 = 0; n2 < 2; ++n2)
#pragma unroll
        for (int kk = 0; kk < 2; ++kk)
          acc[4 + m4][n2] = __builtin_amdgcn_mfma_f32_16x16x32_bf16(
              aF[m4][kk], bF[n2][kk], acc[4 + m4][n2], 0, 0, 0);
    __builtin_amdgcn_s_setprio(0);
    if (!last) { WAITBAR("s_waitcnt vmcnt(4) lgkmcnt(0)") }
    else       { WAITBAR("s_waitcnt vmcnt(0) lgkmcnt(0)") }

    // ---- phase 2: quadrant (mh1, nh1): reuse A, reload B (B-hi)
#pragma unroll
    for (int n2 = 0; n2 < 2; ++n2) {
      bF[n2][0] = *reinterpret_cast<const short8*>(bC + 8192 + n2 * 1024);
      bF[n2][1] = *reinterpret_cast<const short8*>(bC + 8192 + n2 * 1024 + 512);
    }
    if (!last) stage2(gAn + 8192, aN + 8192, tid);  // H2(kt+1)
    __builtin_amdgcn_s_setprio(1);
#pragma unroll
    for (int m4 = 0; m4 < 4; ++m4)
#pragma unroll
      for (int n2 = 0; n2 < 2; ++n2)
#pragma unroll
        for (int kk = 0; kk < 2; ++kk)
          acc[4 + m4][2 + n2] = __builtin_amdgcn_mfma_f32_16x16x32_bf16(
              aF[m4][kk], bF[n2][kk], acc[4 + m4][2 + n2], 0, 0, 0);
    __builtin_amdgcn_s_setprio(0);
    WAITBAR("s_waitcnt lgkmcnt(0)")

    // ---- phase 3: quadrant (mh0, nh1): reload A (A-lo), reuse B
#pragma unroll
    for (int m4 = 0; m4 < 4; ++m4) {
      aF[m4][0] = *reinterpret_cast<const short8*>(aC + m4 * 1024);
      aF[m4][1] = *reinterpret_cast<const short8*>(aC + m4 * 1024 + 512);
    }
    if (!last) stage2(gBn + 8192, bN + 8192, tid);  // H3(kt+1)
    __builtin_amdgcn_s_setprio(1);
#pragma unroll
    for (int m4 = 0; m4 < 4; ++m4)
#pragma unroll
      for (int n2 = 0; n2 < 2; ++n2)
#pragma unroll
        for (int kk = 0; kk < 2; ++kk)
          acc[m4][2 + n2] = __builtin_amdgcn_mfma_f32_16x16x32_bf16(
              aF[m4][kk], bF[n2][kk], acc[m4][2 + n2], 0, 0, 0);
    __builtin_amdgcn_s_setprio(0);
    if (!last) { WAITBAR("s_waitcnt vmcnt(4) lgkmcnt(0)") }
    else       { asm volatile("s_waitcnt lgkmcnt(0)" ::: "memory"); }

    curOff = nxtOff;
  }

  // ---- fused LSTM epilogue (lane-local: acc frag index g == gate)
  int h = bn * 64 + wc * 16 + (lane & 15);
  float vbi = b_i[h], vbf = b_f[h], vbc = b_c[h], vbo = b_o[h];
  int rbase = bm * 256 + wr * 128 + ((lane >> 4) << 2);
  float* outH = out;
  float* outC = out + (uint64_t)B_DIM * H_DIM;
#pragma unroll
  for (int m = 0; m < 8; ++m) {
#pragma unroll
    for (int j = 0; j < 4; ++j) {
      int r = rbase + m * 16 + j;
      float pi = acc[m][0][j] + vbi;
      float pf = acc[m][1][j] + vbf;
      float pc = acc[m][2][j] + vbc;
      float po = acc[m][3][j] + vbo;
      float gi = 1.f / (1.f + __expf(-pi));
      float gf = 1.f / (1.f + __expf(-pf));
      float gc = 1.f - 2.f / (__expf(2.f * pc) + 1.f);  // tanh
      float go = 1.f / (1.f + __expf(-po));
      float zv = z[(uint64_t)r * H_DIM + h];
      float cn = gf * zv + gi * gc;
      float hn = go * (1.f - 2.f / (__expf(2.f * cn) + 1.f));
      outH[(uint64_t)r * H_DIM + h] = hn;
      outC[(uint64_t)r * H_DIM + h] = cn;
    }
  }
}

extern "C" void kernel_launch(void* const* d_in, const int* in_sizes, int n_in,
                              void* d_out, int out_size, void* d_ws, size_t ws_size,
                              hipStream_t stream) {
  const float* z  = (const float*)d_in[0];
  const float* x  = (const float*)d_in[1];
  const float* Wi = (const float*)d_in[2];
  const float* Wf = (const float*)d_in[3];
  const float* Wc = (const float*)d_in[4];
  const float* Wo = (const float*)d_in[5];
  const float* bi = (const float*)d_in[6];
  const float* bf = (const float*)d_in[7];
  const float* bc = (const float*)d_in[8];
  const float* bo = (const float*)d_in[9];
  const float* Ui = (const float*)d_in[10];
  const float* Uf = (const float*)d_in[11];
  const float* Uc = (const float*)d_in[12];
  const float* Uo = (const float*)d_in[13];

  unsigned short* Ap = (unsigned short*)d_ws;                          // 32 MB
  unsigned short* Bp = (unsigned short*)((char*)d_ws
                        + (size_t)B_DIM * KTOT * sizeof(unsigned short)); // +4 MB
  float* out = (float*)d_out;

  hipLaunchKernelGGL(pack_w_kernel, dim3((size_t)NP * KTOT / 8 / 256), dim3(256), 0, stream,
                     Wi, Wf, Wc, Wo, Ui, Uf, Uc, Uo, Bp);
  hipLaunchKernelGGL(pack_a_kernel, dim3((size_t)B_DIM * KTOT / 8 / 256), dim3(256), 0, stream,
                     x, z, Ap);
  hipLaunchKernelGGL(lstm_gemm_kernel, dim3(512), dim3(512), 0, stream,
                     Ap, Bp, z, bi, bf, bc, bo, out);
}